// Round 8
// baseline (318.477 us; speedup 1.0000x reference)
//
#include <hip/hip_runtime.h>
#include <hip/hip_bf16.h>

#define NB 16   // batch
#define NN 512  // input capsules (n)
#define DI 256  // input dim (i)
#define NC 64   // output capsules (c)
#define ND 128  // capsule dim (d)
#define FO 8192 // NC*ND
#define NP 16   // n-tiles (split-k partials for y)

typedef __attribute__((ext_vector_type(8))) short short8v;
typedef __attribute__((ext_vector_type(4))) short short4v;
typedef __attribute__((ext_vector_type(4))) float f32x4;
typedef unsigned short us16;

// ---------------------------------------------------------------------------
// Grid barrier state: zero-init .bss device globals. Ticket protocol is
// monotonic -> needs NO reset across graph replays (each call adds exactly 16
// per group counter and 16 to root; target = round-up-16 of own ticket).
__device__ unsigned g_cnt[5][16][16];  // [barrier][group][pad to 64B line]
__device__ unsigned g_root[5][16];

__device__ __forceinline__ void gridbar(int k) {
  __builtin_amdgcn_fence(__ATOMIC_RELEASE, "agent");   // flush my writes
  __syncthreads();
  if (threadIdx.x == 0) {
    int grp = blockIdx.x & 15;   // 16 blocks per group (256 blocks)
    unsigned t = __hip_atomic_fetch_add(&g_cnt[k][grp][0], 1u,
                     __ATOMIC_RELAXED, __HIP_MEMORY_SCOPE_AGENT) + 1u;
    if ((t & 15u) == 0u)
      __hip_atomic_fetch_add(&g_root[k][0], 1u,
                     __ATOMIC_RELAXED, __HIP_MEMORY_SCOPE_AGENT);
    unsigned target = (t + 15u) & ~15u;
    while ((int)(__hip_atomic_load(&g_root[k][0], __ATOMIC_RELAXED,
                     __HIP_MEMORY_SCOPE_AGENT) - target) < 0)
      __builtin_amdgcn_s_sleep(4);
  }
  __syncthreads();
  __builtin_amdgcn_fence(__ATOMIC_ACQUIRE, "agent");   // invalidate stale lines
}

__device__ __forceinline__ us16 f2b(float f) {
  union { __hip_bfloat16 h; us16 u; } cv; cv.h = __float2bfloat16(f); return cv.u;
}
__device__ __forceinline__ float b2f(us16 u) {
  union { unsigned u; float f; } cv; cv.u = ((unsigned)u) << 16; return cv.f;
}

struct SMEM {
  union {
    struct { float stage[128][68]; float red[8][64]; } p0;                    // 36.9 KB
    struct { float y[4][DI]; f32x4 p[16][4][32]; us16 ob[4][ND]; } ow;        // 37.9 KB
    struct { float s[32][65]; us16 cT[64][40]; } sy;                          // 13.4 KB
  };
};

// ---------------------------------------------------------------------------
// ow phase: block (c = blk&63, b-quad = blk>>6).
//  y-combine -> O_raw[4,128] = Y[4,256].Kc (fp32) -> squash
//  MODE 0: y = xsum/64 (uniform coef), emit w via MFMA
//  MODE 1: y = sum of 16 bf16 partials, emit w via MFMA
//  MODE 2: final -> write out, no w
template <int MODE>
__device__ __forceinline__ void ow_phase(const float* __restrict__ kern,
                                         const us16* __restrict__ kh,
                                         const us16* __restrict__ yp_in,
                                         const float* __restrict__ xsum_p,
                                         us16* __restrict__ whc_out,
                                         float* __restrict__ outp,
                                         SMEM& sm, int blk, int tid) {
  int c = blk & 63, b0 = (blk >> 6) * 4;

  // ---- y combine
  if (tid < 256) {
    int bb = tid >> 6, i4 = tid & 63;
    float4 v;
    if constexpr (MODE == 0) {
      float4 s0 = ((const float4*)(xsum_p + ((size_t)0 * NB + b0 + bb) * DI))[i4];
      float4 s1 = ((const float4*)(xsum_p + ((size_t)1 * NB + b0 + bb) * DI))[i4];
      float4 s2 = ((const float4*)(xsum_p + ((size_t)2 * NB + b0 + bb) * DI))[i4];
      float4 s3 = ((const float4*)(xsum_p + ((size_t)3 * NB + b0 + bb) * DI))[i4];
      v.x = (s0.x + s1.x + s2.x + s3.x) * (1.f / 64.f);
      v.y = (s0.y + s1.y + s2.y + s3.y) * (1.f / 64.f);
      v.z = (s0.z + s1.z + s2.z + s3.z) * (1.f / 64.f);
      v.w = (s0.w + s1.w + s2.w + s3.w) * (1.f / 64.f);
    } else {
      float a0 = 0.f, a1 = 0.f, a2 = 0.f, a3 = 0.f;
      const us16* base = yp_in + ((size_t)(b0 + bb) * NC + c) * DI + i4 * 4;
#pragma unroll
      for (int p = 0; p < NP; ++p) {
        short4v t = *(const short4v*)(base + (size_t)p * (NB * NC * DI));
        a0 += b2f((us16)t[0]); a1 += b2f((us16)t[1]);
        a2 += b2f((us16)t[2]); a3 += b2f((us16)t[3]);
      }
      v.x = a0; v.y = a1; v.z = a2; v.w = a3;
    }
    *(float4*)&sm.ow.y[bb][i4 * 4] = v;
  }
  __syncthreads();

  // ---- phase1 fp32: thread = (i-16th h 0..15, d-quad dq 0..31)
  {
    int dq = tid & 31, h = tid >> 5;
    f32x4 acc[4];
#pragma unroll
    for (int bb = 0; bb < 4; ++bb) { acc[bb][0]=acc[bb][1]=acc[bb][2]=acc[bb][3]=0.f; }
    const float* kp = kern + c * ND + dq * 4;
#pragma unroll 2
    for (int t = 0; t < 16; t += 4) {
      int i = h * 16 + t;
      float4 kv0 = *(const float4*)(kp + (size_t)(i + 0) * FO);
      float4 kv1 = *(const float4*)(kp + (size_t)(i + 1) * FO);
      float4 kv2 = *(const float4*)(kp + (size_t)(i + 2) * FO);
      float4 kv3 = *(const float4*)(kp + (size_t)(i + 3) * FO);
#pragma unroll
      for (int bb = 0; bb < 4; ++bb) {
        float4 yv = *(const float4*)&sm.ow.y[bb][i];
        acc[bb][0] += yv.x * kv0.x + yv.y * kv1.x + yv.z * kv2.x + yv.w * kv3.x;
        acc[bb][1] += yv.x * kv0.y + yv.y * kv1.y + yv.z * kv2.y + yv.w * kv3.y;
        acc[bb][2] += yv.x * kv0.z + yv.y * kv1.z + yv.z * kv2.z + yv.w * kv3.z;
        acc[bb][3] += yv.x * kv0.w + yv.y * kv1.w + yv.z * kv2.w + yv.w * kv3.w;
      }
    }
#pragma unroll
    for (int bb = 0; bb < 4; ++bb) sm.ow.p[h][bb][dq] = acc[bb];
  }
  __syncthreads();

  // ---- combine + squash: tid<128, bb = tid>>5, j = tid&31 (d-quad)
  if (tid < 128) {
    int bb = tid >> 5, j = tid & 31;
    f32x4 o = {0.f, 0.f, 0.f, 0.f};
#pragma unroll
    for (int h = 0; h < 16; ++h) {
      f32x4 p = sm.ow.p[h][bb][j];
      o[0] += p[0]; o[1] += p[1]; o[2] += p[2]; o[3] += p[3];
    }
    float sq = o[0]*o[0] + o[1]*o[1] + o[2]*o[2] + o[3]*o[3];
#pragma unroll
    for (int off = 16; off >= 1; off >>= 1) sq += __shfl_xor(sq, off, 64);
    float tot = sq + 1e-7f;
    float scale = sqrtf(tot) / (0.5f + tot);
    o[0] *= scale; o[1] *= scale; o[2] *= scale; o[3] *= scale;
    if constexpr (MODE == 2) {
      float4 st = {o[0], o[1], o[2], o[3]};
      ((float4*)(outp + ((size_t)(b0 + bb) * NC + c) * ND))[j] = st;
    } else {
      us16* ob = &sm.ow.ob[bb][j * 4];
      ob[0] = f2b(o[0]); ob[1] = f2b(o[1]); ob[2] = f2b(o[2]); ob[3] = f2b(o[3]);
    }
  }
  __syncthreads();

  // ---- w-phase MFMA: w[b,c,i] = sum_d o[b,d]*kern[i][cd]
  //  A[m=b(pad16)][k=d] from ob LDS; B[n=i][k=d] from kh rows (contiguous!).
  //  D rows m>=4 are junk (discarded); ko==0 lanes hold rows 0..3.
  if constexpr (MODE < 2) {
    int lane = tid & 63, w = tid >> 6;
    int m16 = lane & 15, ko = lane >> 4;
#pragma unroll
    for (int nt = 0; nt < 2; ++nt) {
      int i0 = (w * 2 + nt) * 16;
      f32x4 acc = {0.f, 0.f, 0.f, 0.f};
#pragma unroll
      for (int kk = 0; kk < 4; ++kk) {
        short8v av = *(const short8v*)&sm.ow.ob[m16 & 3][kk * 32 + ko * 8];
        short8v bv = *(const short8v*)(kh + (size_t)(i0 + m16) * FO + c * ND + kk * 32 + ko * 8);
        acc = __builtin_amdgcn_mfma_f32_16x16x32_bf16(av, bv, acc, 0, 0, 0);
      }
      if (ko == 0) {
#pragma unroll
        for (int r = 0; r < 4; ++r)
          whc_out[((size_t)(b0 + r) * NC + c) * DI + i0 + m16] = f2b(acc[r]);
      }
    }
  }
}

// ---------------------------------------------------------------------------
// sy phase: block (b = blk>>4, p = blk&15), 32-n tile. Round-7 k_sy with
// logits carried in registers (keep[]) instead of global blog.
template <bool ADD>
__device__ __forceinline__ void sy_phase(const us16* __restrict__ xh,
                                         const us16* __restrict__ xhT,
                                         const us16* __restrict__ whc,
                                         us16* __restrict__ yp_out,
                                         SMEM& sm, int blk, int tid, float* keep) {
  int b = blk >> 4, p = blk & 15;
  int lane = tid & 63, w = tid >> 6;
  int m16 = lane & 15, ko = lane >> 4;
  int n0 = p * 32;

  // ---- logits sT[c][n] = sum_i w[c][i]*x[n][i]
  {
    int Mt = w & 3, Nt = w >> 2;
    const us16* wrow = whc + ((size_t)b * NC + Mt * 16 + m16) * DI + ko * 8;
    const us16* xrow = xh + ((size_t)b * NN + n0 + Nt * 16 + m16) * DI + ko * 8;
    f32x4 acc = {0.f, 0.f, 0.f, 0.f};
#pragma unroll
    for (int k8 = 0; k8 < 8; ++k8) {
      short8v av = *(const short8v*)(wrow + k8 * 32);
      short8v bv = *(const short8v*)(xrow + k8 * 32);
      acc = __builtin_amdgcn_mfma_f32_16x16x32_bf16(av, bv, acc, 0, 0, 0);
    }
#pragma unroll
    for (int r = 0; r < 4; ++r)
      sm.sy.s[Nt * 16 + m16][Mt * 16 + ko * 4 + r] = acc[r];
  }
  __syncthreads();

  // ---- softmax over c (lane = c); wave w owns n = w*4..+3
  {
    us16 pk[4];
#pragma unroll
    for (int nn = 0; nn < 4; ++nn) {
      int n = w * 4 + nn;
      float v = sm.sy.s[n][lane];
      if (ADD) v += keep[nn];
      keep[nn] = v;
      float m = v;
#pragma unroll
      for (int off = 32; off >= 1; off >>= 1) m = fmaxf(m, __shfl_xor(m, off, 64));
      float e = __expf(v - m);
      float s = e;
#pragma unroll
      for (int off = 32; off >= 1; off >>= 1) s += __shfl_xor(s, off, 64);
      pk[nn] = f2b(e / s);
    }
    *(short4v*)&sm.sy.cT[lane][w * 4] = *(short4v*)pk;
  }
  __syncthreads();

  // ---- y partials: y_p[p][b][c][i] = sum_n coef[c][n]*x[n][i]  (bf16 out)
  {
    int Mp = w >> 2, Ng = w & 3;
    short8v a0 = *(const short8v*)&sm.sy.cT[(Mp * 2 + 0) * 16 + m16][ko * 8];
    short8v a1 = *(const short8v*)&sm.sy.cT[(Mp * 2 + 1) * 16 + m16][ko * 8];
    f32x4 acc[2][4];
#pragma unroll
    for (int t = 0; t < 2; ++t)
#pragma unroll
      for (int q = 0; q < 4; ++q) { acc[t][q][0]=acc[t][q][1]=acc[t][q][2]=acc[t][q][3]=0.f; }
#pragma unroll
    for (int q = 0; q < 4; ++q) {
      int icol = (Ng * 4 + q) * 16 + m16;
      short8v bv = *(const short8v*)(xhT + ((size_t)b * DI + icol) * NN + n0 + ko * 8);
      acc[0][q] = __builtin_amdgcn_mfma_f32_16x16x32_bf16(a0, bv, acc[0][q], 0, 0, 0);
      acc[1][q] = __builtin_amdgcn_mfma_f32_16x16x32_bf16(a1, bv, acc[1][q], 0, 0, 0);
    }
    us16* yb = yp_out + ((size_t)p * NB + b) * (NC * DI);
#pragma unroll
    for (int t = 0; t < 2; ++t)
#pragma unroll
      for (int q = 0; q < 4; ++q)
#pragma unroll
        for (int r = 0; r < 4; ++r)
          yb[(size_t)((Mp * 2 + t) * 16 + ko * 4 + r) * DI + (Ng * 4 + q) * 16 + m16] =
              f2b(acc[t][q][r]);
  }
}

// ---------------------------------------------------------------------------
__global__ __launch_bounds__(512) void caps_all(const float* __restrict__ x,
                                                const float* __restrict__ kern,
                                                float* __restrict__ out,
                                                us16* __restrict__ kh,
                                                us16* __restrict__ xh,
                                                us16* __restrict__ xhT,
                                                float* __restrict__ xsum_p,
                                                us16* __restrict__ whcA,
                                                us16* __restrict__ whcB,
                                                us16* __restrict__ ypA,
                                                us16* __restrict__ ypB) {
  __shared__ SMEM sm;
  int blk = blockIdx.x, tid = threadIdx.x;
  float keep[4];

  // ================= P0: prep (xh, xhT, colsum; kh on blocks<128) ==========
  {
    int b = blk >> 4, nq = (blk >> 2) & 3, ic = blk & 3;  // 128-n x 64-i tile
#pragma unroll
    for (int t = 0; t < 4; ++t) {
      int e4 = tid + t * 512;            // 0..2047 = 128 rows x 16 float4
      int nl = e4 >> 4, q4 = e4 & 15;
      float4 v = *(const float4*)(x + ((size_t)b * NN + nq * 128 + nl) * DI + ic * 64 + q4 * 4);
      *(float4*)&sm.p0.stage[nl][q4 * 4] = v;
    }
    __syncthreads();
    {  // xh row-major bf16
      int nl = tid >> 2, ig = (tid & 3) * 16;
      us16 tmp[16];
#pragma unroll
      for (int e = 0; e < 16; ++e) tmp[e] = f2b(sm.p0.stage[nl][ig + e]);
      us16* dst = xh + ((size_t)b * NN + nq * 128 + nl) * DI + ic * 64 + ig;
      *(short8v*)dst = *(short8v*)tmp;
      *(short8v*)(dst + 8) = *(short8v*)(tmp + 8);
    }
    {  // xhT transposed bf16
      int il = tid & 63, ng = tid >> 6;
      us16 tmp[16];
#pragma unroll
      for (int e = 0; e < 16; ++e) tmp[e] = f2b(sm.p0.stage[ng * 16 + e][il]);
      us16* dst = xhT + ((size_t)b * DI + ic * 64 + il) * NN + nq * 128 + ng * 16;
      *(short8v*)dst = *(short8v*)tmp;
      *(short8v*)(dst + 8) = *(short8v*)(tmp + 8);
    }
    {  // colsum partials
      int il = tid & 63, rg = tid >> 6;
      float s = 0.f;
#pragma unroll
      for (int r = 0; r < 16; ++r) s += sm.p0.stage[rg * 16 + r][il];
      sm.p0.red[rg][il] = s;
    }
    __syncthreads();
    if (tid < 64) {
      float t = 0.f;
#pragma unroll
      for (int g = 0; g < 8; ++g) t += sm.p0.red[g][tid];
      xsum_p[((size_t)nq * NB + b) * DI + ic * 64 + tid] = t;
    }
    if (blk < 128) {  // kern -> bf16 (same layout)
#pragma unroll
      for (int t = 0; t < 8; ++t) {
        size_t e = (size_t)blk * 16384 + (size_t)t * 2048 + (size_t)tid * 4;
        float4 v = *(const float4*)(kern + e);
        us16 tmp[4] = {f2b(v.x), f2b(v.y), f2b(v.z), f2b(v.w)};
        *(short4v*)(kh + e) = *(short4v*)tmp;
      }
    }
  }
  gridbar(0);
  // ================= iteration 0 ===========================================
  ow_phase<0>(kern, kh, nullptr, xsum_p, whcA, nullptr, sm, blk, tid);
  gridbar(1);
  // ================= iteration 1 ===========================================
  sy_phase<false>(xh, xhT, whcA, ypA, sm, blk, tid, keep);
  gridbar(2);
  ow_phase<1>(kern, kh, ypA, nullptr, whcB, nullptr, sm, blk, tid);
  gridbar(3);
  // ================= iteration 2 ===========================================
  sy_phase<true>(xh, xhT, whcB, ypB, sm, blk, tid, keep);
  gridbar(4);
  ow_phase<2>(kern, kh, ypB, nullptr, nullptr, out, sm, blk, tid);
}

// ---------------------------------------------------------------------------
extern "C" void kernel_launch(void* const* d_in, const int* in_sizes, int n_in,
                              void* d_out, int out_size, void* d_ws, size_t ws_size,
                              hipStream_t stream) {
  (void)in_sizes; (void)n_in; (void)out_size; (void)ws_size;
  const float* x    = (const float*)d_in[0];   // [16,512,256]
  const float* kern = (const float*)d_in[1];   // [256,8192]
  float* out = (float*)d_out;                  // [16,64,128]

  char* w = (char*)d_ws;                               // ~29 MB total
  us16* kh   = (us16*)w;  w += (size_t)DI * FO * 2;          // 4 MB
  us16* xh   = (us16*)w;  w += (size_t)NB * NN * DI * 2;     // 4 MB
  us16* xhT  = (us16*)w;  w += (size_t)NB * DI * NN * 2;     // 4 MB
  us16* whcA = (us16*)w;  w += (size_t)NB * NC * DI * 2;     // 512 KB
  us16* whcB = (us16*)w;  w += (size_t)NB * NC * DI * 2;     // 512 KB
  us16* ypA  = (us16*)w;  w += (size_t)NP * NB * NC * DI * 2; // 8 MB
  us16* ypB  = (us16*)w;  w += (size_t)NP * NB * NC * DI * 2; // 8 MB
  float* xsum_p = (float*)w;                                 // 64 KB

  caps_all<<<256, 512, 0, stream>>>(x, kern, out, kh, xh, xhT, xsum_p,
                                    whcA, whcB, ypA, ypB);
}

// Round 9
// 61.040 us; speedup vs baseline: 5.2176x; 5.2176x over previous
//
#include <hip/hip_runtime.h>
#include <hip/hip_bf16.h>

#define NB 16   // batch
#define NN 512  // input capsules (n)
#define DI 256  // input dim (i)
#define NC 64   // output capsules (c)
#define ND 128  // capsule dim (d)
#define FO 8192 // NC*ND
#define NP 16   // n-tiles (split-k partials for y)

typedef __attribute__((ext_vector_type(8))) short short8v;
typedef __attribute__((ext_vector_type(4))) short short4v;
typedef __attribute__((ext_vector_type(4))) float f32x4;
typedef unsigned short us16;

__device__ __forceinline__ us16 f2b(float f) {
  union { __hip_bfloat16 h; us16 u; } cv; cv.h = __float2bfloat16(f); return cv.u;
}
__device__ __forceinline__ float b2f(us16 u) {
  union { unsigned u; float f; } cv; cv.u = ((unsigned)u) << 16; return cv.f;
}

// ---------------------------------------------------------------------------
// k_pre: task-split prep.
//  [0,512):     khT[c][d][i] = bf16(kern[i][c*128+d])   (transpose, LDS-tiled)
//  [512,1024):  xh[b][n][i], xhT[b][i][n]  bf16 casts of x
//  [1024,1088): xsum_p[q][b][i] colsum quarters
//  [1088,1216): kh[i][cd] = bf16(kern) same layout
__global__ __launch_bounds__(256) void k_pre(const float* __restrict__ x,
                                             const float* __restrict__ kern,
                                             us16* __restrict__ khT,
                                             us16* __restrict__ kh,
                                             us16* __restrict__ xh,
                                             us16* __restrict__ xhT,
                                             float* __restrict__ xsum_p) {
  int task = blockIdx.x;
  int tid = threadIdx.x;

  if (task < 512) {  // khT bf16 transpose
    int c = task >> 3, i0 = (task & 7) * 32;
    __shared__ float buf[32][129];
#pragma unroll
    for (int k = 0; k < 4; ++k) {
      int e4 = tid + k * 256;
      int r = e4 >> 5, dq = e4 & 31;
      float4 v = *(const float4*)(kern + (size_t)(i0 + r) * FO + c * ND + dq * 4);
      buf[r][dq * 4 + 0] = v.x; buf[r][dq * 4 + 1] = v.y;
      buf[r][dq * 4 + 2] = v.z; buf[r][dq * 4 + 3] = v.w;
    }
    __syncthreads();
#pragma unroll
    for (int k = 0; k < 16; ++k) {
      int e = tid + k * 256;
      int il = e & 31, d = e >> 5;
      khT[((size_t)c * ND + d) * DI + i0 + il] = f2b(buf[il][d]);
    }
  } else if (task < 1024) {  // xh / xhT
    int idx = task - 512;
    int b = idx >> 5, rem = idx & 31;
    int nb = (rem >> 2) * 64, ib = (rem & 3) * 64;
    __shared__ float buf2[64][68];
#pragma unroll
    for (int k = 0; k < 4; ++k) {
      int e4 = tid + k * 256;
      int nl = e4 >> 4, q4 = e4 & 15;
      float4 v = *(const float4*)(x + ((size_t)b * NN + nb + nl) * DI + ib + q4 * 4);
      *(float4*)&buf2[nl][q4 * 4] = v;
    }
    __syncthreads();
    {
      int nl = tid >> 2, ig = (tid & 3) * 16;
      us16 tmp[16];
#pragma unroll
      for (int e = 0; e < 16; ++e) tmp[e] = f2b(buf2[nl][ig + e]);
      us16* dst = xh + ((size_t)b * NN + nb + nl) * DI + ib + ig;
      *(short8v*)dst = *(short8v*)tmp;
      *(short8v*)(dst + 8) = *(short8v*)(tmp + 8);
    }
    {
      int il = tid & 63, ng = tid >> 6;
      us16 tmp[16];
#pragma unroll
      for (int e = 0; e < 16; ++e) tmp[e] = f2b(buf2[ng * 16 + e][il]);
      us16* dst = xhT + ((size_t)b * DI + ib + il) * NN + nb + ng * 16;
      *(short8v*)dst = *(short8v*)tmp;
      *(short8v*)(dst + 8) = *(short8v*)(tmp + 8);
    }
  } else if (task < 1088) {  // colsum
    int idx = task - 1024;
    int b = idx >> 2, q = idx & 3;
    int ns = tid >> 6, i4 = tid & 63;
    float4 a = {0.f, 0.f, 0.f, 0.f};
    const float4* xp = (const float4*)(x + ((size_t)b * NN + q * 128 + ns * 32) * DI) + i4;
#pragma unroll 4
    for (int n = 0; n < 32; ++n) {
      float4 v = xp[(size_t)n * 64];
      a.x += v.x; a.y += v.y; a.z += v.z; a.w += v.w;
    }
    __shared__ float4 red[4][64];
    red[ns][i4] = a;
    __syncthreads();
    if (ns == 0) {
      float4 s0 = red[0][i4], s1 = red[1][i4], s2 = red[2][i4], s3 = red[3][i4];
      float4 s;
      s.x = s0.x + s1.x + s2.x + s3.x;  s.y = s0.y + s1.y + s2.y + s3.y;
      s.z = s0.z + s1.z + s2.z + s3.z;  s.w = s0.w + s1.w + s2.w + s3.w;
      ((float4*)(xsum_p + ((size_t)q * NB + b) * DI))[i4] = s;
    }
  } else {  // kh cast (same layout)
    int blk2 = task - 1088;  // 0..127
#pragma unroll
    for (int t = 0; t < 16; ++t) {
      size_t e = (size_t)blk2 * 16384 + (size_t)t * 1024 + (size_t)tid * 4;
      float4 v = *(const float4*)(kern + e);
      us16 tmp[4] = {f2b(v.x), f2b(v.y), f2b(v.z), f2b(v.w)};
      *(short4v*)(kh + e) = *(short4v*)tmp;
    }
  }
}

// ---------------------------------------------------------------------------
// k_owm: all-MFMA o+w for iterations 0/1. Block (c, b-quad), 256 thr.
//  O_raw[b,d] = sum_i y[b,i]*khT[c,d,i]  (A=y rows b pad16, B=khT rows d)
//  squash -> ob bf16 ; w[b,c,i] = sum_d o[b,d]*kh[i][cd]  (B=kh rows i)
template <bool FIRST>
__global__ __launch_bounds__(256) void k_owm(const us16* __restrict__ khT,
                                             const us16* __restrict__ kh,
                                             const us16* __restrict__ yp_in,
                                             const float* __restrict__ xsum_p,
                                             us16* __restrict__ whc) {
  int c = blockIdx.x, b0 = blockIdx.y * 4;
  int tid = threadIdx.x;
  int lane = tid & 63, w = tid >> 6;
  int m16 = lane & 15, ko = lane >> 4;

  __shared__ us16 ybf[16][DI];     // 8 KB (rows 4..15 zero)
  __shared__ float o_f32[4][ND];   // 2 KB
  __shared__ us16 ob[4][ND];       // 1 KB

  // ---- y combine -> bf16 A rows
  {
    int bb = tid >> 6, i4 = tid & 63;
    float4 v;
    if constexpr (FIRST) {
      float4 s0 = ((const float4*)(xsum_p + ((size_t)0 * NB + b0 + bb) * DI))[i4];
      float4 s1 = ((const float4*)(xsum_p + ((size_t)1 * NB + b0 + bb) * DI))[i4];
      float4 s2 = ((const float4*)(xsum_p + ((size_t)2 * NB + b0 + bb) * DI))[i4];
      float4 s3 = ((const float4*)(xsum_p + ((size_t)3 * NB + b0 + bb) * DI))[i4];
      v.x = (s0.x + s1.x + s2.x + s3.x) * (1.f / 64.f);
      v.y = (s0.y + s1.y + s2.y + s3.y) * (1.f / 64.f);
      v.z = (s0.z + s1.z + s2.z + s3.z) * (1.f / 64.f);
      v.w = (s0.w + s1.w + s2.w + s3.w) * (1.f / 64.f);
    } else {
      float a0 = 0.f, a1 = 0.f, a2 = 0.f, a3 = 0.f;
      const us16* base = yp_in + ((size_t)(b0 + bb) * NC + c) * DI + i4 * 4;
#pragma unroll
      for (int p = 0; p < NP; ++p) {
        short4v t = *(const short4v*)(base + (size_t)p * (NB * NC * DI));
        a0 += b2f((us16)t[0]); a1 += b2f((us16)t[1]);
        a2 += b2f((us16)t[2]); a3 += b2f((us16)t[3]);
      }
      v.x = a0; v.y = a1; v.z = a2; v.w = a3;
    }
    us16 tmp[4] = {f2b(v.x), f2b(v.y), f2b(v.z), f2b(v.w)};
    *(short4v*)&ybf[bb][i4 * 4] = *(short4v*)tmp;
#pragma unroll
    for (int r = 0; r < 12; ++r) ybf[4 + r][tid] = 0;  // zero pad rows
  }
  __syncthreads();

  // ---- O_raw MFMA: wave w covers d-tiles (w*2+nt)*16, nt 0..1; K=256
  {
#pragma unroll
    for (int nt = 0; nt < 2; ++nt) {
      int d0 = (w * 2 + nt) * 16;
      f32x4 acc = {0.f, 0.f, 0.f, 0.f};
#pragma unroll
      for (int kk = 0; kk < 8; ++kk) {
        short8v av = *(const short8v*)&ybf[m16][kk * 32 + ko * 8];
        short8v bv = *(const short8v*)(khT + ((size_t)c * ND + d0 + m16) * DI + kk * 32 + ko * 8);
        acc = __builtin_amdgcn_mfma_f32_16x16x32_bf16(av, bv, acc, 0, 0, 0);
      }
      if (ko == 0) {
#pragma unroll
        for (int r = 0; r < 4; ++r) o_f32[r][d0 + m16] = acc[r];
      }
    }
  }
  __syncthreads();

  // ---- squash (tid<128: bb = tid>>5, j = tid&31 d-quad)
  if (tid < 128) {
    int bb = tid >> 5, j = tid & 31;
    float4 o = *(const float4*)&o_f32[bb][j * 4];
    float sq = o.x * o.x + o.y * o.y + o.z * o.z + o.w * o.w;
#pragma unroll
    for (int off = 16; off >= 1; off >>= 1) sq += __shfl_xor(sq, off, 64);
    float tot = sq + 1e-7f;
    float scale = sqrtf(tot) / (0.5f + tot);
    us16 tmp[4] = {f2b(o.x * scale), f2b(o.y * scale), f2b(o.z * scale), f2b(o.w * scale)};
    *(short4v*)&ob[bb][j * 4] = *(short4v*)tmp;
  }
  __syncthreads();

  // ---- w-phase MFMA: A = ob rows (b mod 4), B = kh rows i; K=d=128
  {
#pragma unroll
    for (int nt = 0; nt < 4; ++nt) {
      int i0 = (w * 4 + nt) * 16;
      f32x4 acc = {0.f, 0.f, 0.f, 0.f};
#pragma unroll
      for (int kk = 0; kk < 4; ++kk) {
        short8v av = *(const short8v*)&ob[m16 & 3][kk * 32 + ko * 8];
        short8v bv = *(const short8v*)(kh + (size_t)(i0 + m16) * FO + c * ND + kk * 32 + ko * 8);
        acc = __builtin_amdgcn_mfma_f32_16x16x32_bf16(av, bv, acc, 0, 0, 0);
      }
      if (ko == 0) {
#pragma unroll
        for (int r = 0; r < 4; ++r)
          whc[((size_t)(b0 + r) * NC + c) * DI + i0 + m16] = f2b(acc[r]);
      }
    }
  }
}

// ---------------------------------------------------------------------------
// k_sy: MFMA fused (logits -> softmax -> partial-y bf16). Round-7-proven.
template <bool ADD_B, bool STORE_B>
__global__ __launch_bounds__(512) void k_sy(const us16* __restrict__ xh,
                                            const us16* __restrict__ xhT,
                                            const us16* __restrict__ whc,
                                            float* __restrict__ blog,
                                            us16* __restrict__ y_p) {
  int b = blockIdx.x, p = blockIdx.y;
  int tid = threadIdx.x;
  int lane = tid & 63, w = tid >> 6;
  int m16 = lane & 15, ko = lane >> 4;

  __shared__ float s_lds[32][65];
  __shared__ us16 cT[64][40];

  int n0 = p * 32;

  {  // logits sT[c][n]
    int Mt = w & 3, Nt = w >> 2;
    const us16* wrow = whc + ((size_t)b * NC + Mt * 16 + m16) * DI + ko * 8;
    const us16* xrow = xh + ((size_t)b * NN + n0 + Nt * 16 + m16) * DI + ko * 8;
    f32x4 acc = {0.f, 0.f, 0.f, 0.f};
#pragma unroll
    for (int k8 = 0; k8 < 8; ++k8) {
      short8v av = *(const short8v*)(wrow + k8 * 32);
      short8v bv = *(const short8v*)(xrow + k8 * 32);
      acc = __builtin_amdgcn_mfma_f32_16x16x32_bf16(av, bv, acc, 0, 0, 0);
    }
#pragma unroll
    for (int r = 0; r < 4; ++r)
      s_lds[Nt * 16 + m16][Mt * 16 + ko * 4 + r] = acc[r];
  }
  __syncthreads();

  {  // softmax over c (lane = c); wave w owns n = w*4..+3
    us16 pk[4];
#pragma unroll
    for (int nn = 0; nn < 4; ++nn) {
      int n = w * 4 + nn;
      float v = s_lds[n][lane];
      size_t gi = ((size_t)b * NN + n0 + n) * NC + lane;
      if (ADD_B) v += blog[gi];
      if (STORE_B) blog[gi] = v;
      float m = v;
#pragma unroll
      for (int off = 32; off >= 1; off >>= 1) m = fmaxf(m, __shfl_xor(m, off, 64));
      float e = __expf(v - m);
      float s = e;
#pragma unroll
      for (int off = 32; off >= 1; off >>= 1) s += __shfl_xor(s, off, 64);
      pk[nn] = f2b(e / s);
    }
    *(short4v*)&cT[lane][w * 4] = *(short4v*)pk;
  }
  __syncthreads();

  {  // y partials (bf16)
    int Mp = w >> 2, Ng = w & 3;
    short8v a0 = *(const short8v*)&cT[(Mp * 2 + 0) * 16 + m16][ko * 8];
    short8v a1 = *(const short8v*)&cT[(Mp * 2 + 1) * 16 + m16][ko * 8];
    f32x4 acc[2][4];
#pragma unroll
    for (int t = 0; t < 2; ++t)
#pragma unroll
      for (int q = 0; q < 4; ++q) { acc[t][q][0]=acc[t][q][1]=acc[t][q][2]=acc[t][q][3]=0.f; }
#pragma unroll
    for (int q = 0; q < 4; ++q) {
      int icol = (Ng * 4 + q) * 16 + m16;
      short8v bv = *(const short8v*)(xhT + ((size_t)b * DI + icol) * NN + n0 + ko * 8);
      acc[0][q] = __builtin_amdgcn_mfma_f32_16x16x32_bf16(a0, bv, acc[0][q], 0, 0, 0);
      acc[1][q] = __builtin_amdgcn_mfma_f32_16x16x32_bf16(a1, bv, acc[1][q], 0, 0, 0);
    }
    us16* yb = y_p + ((size_t)p * NB + b) * (NC * DI);
#pragma unroll
    for (int t = 0; t < 2; ++t)
#pragma unroll
      for (int q = 0; q < 4; ++q)
#pragma unroll
        for (int r = 0; r < 4; ++r)
          yb[(size_t)((Mp * 2 + t) * 16 + ko * 4 + r) * DI + (Ng * 4 + q) * 16 + m16] =
              f2b(acc[t][q][r]);
  }
}

// ---------------------------------------------------------------------------
// k_of: FINAL o (fp32 kern path for accuracy) -> out. Block (c, b-quad).
__global__ __launch_bounds__(256) void k_of(const float* __restrict__ kern,
                                            const us16* __restrict__ yp_in,
                                            float* __restrict__ outp) {
  int c = blockIdx.x, b0 = blockIdx.y * 4;
  int tid = threadIdx.x;
  __shared__ float y_lds[4][DI];
  __shared__ f32x4 p_lds[8][4][32];

  {  // y combine from bf16 partials (fp32 sum)
    int bb = tid >> 6, i4 = tid & 63;
    float a0 = 0.f, a1 = 0.f, a2 = 0.f, a3 = 0.f;
    const us16* base = yp_in + ((size_t)(b0 + bb) * NC + c) * DI + i4 * 4;
#pragma unroll
    for (int p = 0; p < NP; ++p) {
      short4v t = *(const short4v*)(base + (size_t)p * (NB * NC * DI));
      a0 += b2f((us16)t[0]); a1 += b2f((us16)t[1]);
      a2 += b2f((us16)t[2]); a3 += b2f((us16)t[3]);
    }
    float4 v = {a0, a1, a2, a3};
    *(float4*)&y_lds[bb][i4 * 4] = v;
  }
  __syncthreads();

  {  // phase1 fp32: thread = (i-half h 0..7, d-quad dq 0..31)
    int dq = tid & 31, h = tid >> 5;
    f32x4 acc[4];
#pragma unroll
    for (int bb = 0; bb < 4; ++bb) { acc[bb][0]=acc[bb][1]=acc[bb][2]=acc[bb][3]=0.f; }
    const float* kp = kern + c * ND + dq * 4;
#pragma unroll 2
    for (int t = 0; t < 32; t += 4) {
      int i = h * 32 + t;
      float4 kv0 = *(const float4*)(kp + (size_t)(i + 0) * FO);
      float4 kv1 = *(const float4*)(kp + (size_t)(i + 1) * FO);
      float4 kv2 = *(const float4*)(kp + (size_t)(i + 2) * FO);
      float4 kv3 = *(const float4*)(kp + (size_t)(i + 3) * FO);
#pragma unroll
      for (int bb = 0; bb < 4; ++bb) {
        float4 yv = *(const float4*)&y_lds[bb][i];
        acc[bb][0] += yv.x * kv0.x + yv.y * kv1.x + yv.z * kv2.x + yv.w * kv3.x;
        acc[bb][1] += yv.x * kv0.y + yv.y * kv1.y + yv.z * kv2.y + yv.w * kv3.y;
        acc[bb][2] += yv.x * kv0.z + yv.y * kv1.z + yv.z * kv2.z + yv.w * kv3.z;
        acc[bb][3] += yv.x * kv0.w + yv.y * kv1.w + yv.z * kv2.w + yv.w * kv3.w;
      }
    }
#pragma unroll
    for (int bb = 0; bb < 4; ++bb) p_lds[h][bb][dq] = acc[bb];
  }
  __syncthreads();

  if (tid < 128) {  // combine + squash -> out
    int bb = tid >> 5, j = tid & 31;
    f32x4 o = {0.f, 0.f, 0.f, 0.f};
#pragma unroll
    for (int h = 0; h < 8; ++h) {
      f32x4 p = p_lds[h][bb][j];
      o[0] += p[0]; o[1] += p[1]; o[2] += p[2]; o[3] += p[3];
    }
    float sq = o[0]*o[0] + o[1]*o[1] + o[2]*o[2] + o[3]*o[3];
#pragma unroll
    for (int off = 16; off >= 1; off >>= 1) sq += __shfl_xor(sq, off, 64);
    float tot = sq + 1e-7f;
    float scale = sqrtf(tot) / (0.5f + tot);
    float4 st = {o[0] * scale, o[1] * scale, o[2] * scale, o[3] * scale};
    ((float4*)(outp + ((size_t)(b0 + bb) * NC + c) * ND))[j] = st;
  }
}

// ---------------------------------------------------------------------------
extern "C" void kernel_launch(void* const* d_in, const int* in_sizes, int n_in,
                              void* d_out, int out_size, void* d_ws, size_t ws_size,
                              hipStream_t stream) {
  (void)in_sizes; (void)n_in; (void)out_size; (void)ws_size;
  const float* x    = (const float*)d_in[0];   // [16,512,256]
  const float* kern = (const float*)d_in[1];   // [256,8192]
  float* out = (float*)d_out;                  // [16,64,128]

  char* wp = (char*)d_ws;
  us16* khT  = (us16*)wp;  wp += (size_t)NC * ND * DI * 2;       // 4 MB
  us16* kh   = (us16*)wp;  wp += (size_t)DI * FO * 2;            // 4 MB
  us16* xh   = (us16*)wp;  wp += (size_t)NB * NN * DI * 2;       // 4 MB
  us16* xhT  = (us16*)wp;  wp += (size_t)NB * DI * NN * 2;       // 4 MB
  us16* whc  = (us16*)wp;  wp += (size_t)NB * NC * DI * 2;       // 512 KB
  us16* y_p  = (us16*)wp;  wp += (size_t)NP * NB * NC * DI * 2;  // 8 MB
  float* blog   = (float*)wp;  wp += (size_t)NB * NN * NC * 4;   // 2 MB
  float* xsum_p = (float*)wp;                                    // 64 KB

  k_pre<<<1216, 256, 0, stream>>>(x, kern, khT, kh, xh, xhT, xsum_p);

  // iteration 0: uniform coef -> o0 -> w0
  k_owm<true><<<dim3(NC, 4), 256, 0, stream>>>(khT, kh, y_p, xsum_p, whc);
  // iteration 1
  k_sy<false, true><<<dim3(NB, NP), 512, 0, stream>>>(xh, xhT, whc, blog, y_p);
  k_owm<false><<<dim3(NC, 4), 256, 0, stream>>>(khT, kh, y_p, xsum_p, whc);
  // iteration 2
  k_sy<true, false><<<dim3(NB, NP), 512, 0, stream>>>(xh, xhT, whc, blog, y_p);
  k_of<<<dim3(NC, 4), 256, 0, stream>>>(kern, y_p, out);
}